// Round 7
// baseline (318.320 us; speedup 1.0000x reference)
//
#include <hip/hip_runtime.h>
#include <hip/hip_bf16.h>

#define B_ 8
#define H_ 128
#define W_ 256
#define PH 130          // H + 2 zero-pad rows
#define PW 258          // W + 2 zero-pad cols
#define NPIX (B_*64*H_*W_)

typedef short short8  __attribute__((ext_vector_type(8)));  // 8 bf16 (4 VGPRs)
typedef short short4v __attribute__((ext_vector_type(4)));  // 4 bf16 (8 B)
typedef float floatx4 __attribute__((ext_vector_type(4)));  // MFMA C/D

// ---------------------------------------------------------------------------
// Implicit-GEMM 3x3 SAME conv + bias + ReLU, bf16 MFMA 16x16x32, LDS-staged.
// Tile = 4 output rows x 64 px x all Co; 4 waves, wave r owns row r.
// R11 (two additive, independently-revertible changes on the proven R6):
//  * T1 XCD swizzle on ALL conv grids: l=(f&7)*256+f/8 (bijective, 2048%8=0).
//    ty-adjacent tiles (sharing 2 halo rows) + same-image tiles land on one
//    XCD -> halo reads hit that XCD's L2 (200cy) instead of HBM (900cy).
//  * conv2/3/4 staging via global_load_lds width=16 with PRE-SWIZZLED global
//    source + linear LDS dest (m173 pattern): LDS contents bit-identical to
//    the old swizzled ds_write, but no VGPR round-trip (m97: +67% staging).
//    conv1 keeps fp32->bf16 convert staging (DMA path can't convert).
// ---------------------------------------------------------------------------
template<int Ci, int Co, bool LOSS, bool NCHW_IN>
struct conv_cfg {
    static constexpr int SCI  = NCHW_IN ? 32 : Ci;     // slab-resident channels
    static constexpr int PXB  = SCI*2;
    static constexpr int ROWW = NCHW_IN ? 68 : 66;     // slab row width (px)
    static constexpr int SLAB = 6*ROWW*PXB;
    static constexpr int EPIW = 64*(Co+8)*2;
    static constexpr int RECB = 64*272*2;
    static constexpr int LDSZ = LOSS ? (RECB > SLAB ? RECB : SLAB)
                                     : (4*EPIW > SLAB ? 4*EPIW : SLAB);
};

// async global->LDS, 16B per lane (literal size arg required).
__device__ __forceinline__
void gload_lds16(const __hip_bfloat16* g, char* l)
{
    __builtin_amdgcn_global_load_lds(
        (const __attribute__((address_space(1))) void*)g,
        (__attribute__((address_space(3))) void*)l, 16, 0, 0);
}

template<int Ci, int Co, bool LOSS, bool NCHW_IN, bool AVG>
__device__ __forceinline__
void conv_tile(int tx, int ty, int bz, int mz,
               char* __restrict__ slab, float* __restrict__ wred,
               const void* __restrict__ inA,    // m0 input (bf16 NHWC / fp32 NCHW)
               const void* __restrict__ inB,    // m1 input
               const __hip_bfloat16* __restrict__ wt,   // [KC][Co][32] bf16
               const float* __restrict__ bias,
               __hip_bfloat16* __restrict__ outp,       // padded NHWC per-m
               size_t out_mstride,
               const float* __restrict__ ref0,          // fp32 NCHW (LOSS)
               const float* __restrict__ ref1,
               const float* __restrict__ other,         // feat0 (AVG, mz=1 only)
               float* __restrict__ avg_out,
               float* __restrict__ acc_out)
{
    constexpr int CC   = (Ci >= 32) ? Ci/32 : 1;
    constexpr int PXB  = conv_cfg<Ci,Co,LOSS,NCHW_IN>::PXB;
    constexpr int NCB  = PXB/16;
    constexpr int ROWW = conv_cfg<Ci,Co,LOSS,NCHW_IN>::ROWW;
    constexpr int SLAB = conv_cfg<Ci,Co,LOSS,NCHW_IN>::SLAB;
    constexpr int NT   = Co/16;
    constexpr int GNT  = (NT >= 2) ? 2 : 1;
    constexpr int NG   = NT / GNT;
    constexpr int EPIW = conv_cfg<Ci,Co,LOSS,NCHW_IN>::EPIW;

    const int tid  = threadIdx.x;
    const int lane = tid & 63;
    const int wid  = tid >> 6;
    const int col  = lane & 15;
    const int quad = lane >> 4;
    const int w0   = tx * 64;
    const int h0   = ty * 4;
    const int r    = wid;

    __syncthreads();        // prior tile's slab reads complete before restage

    floatx4 acc[4][NT];
#pragma unroll
    for (int mt = 0; mt < 4; ++mt)
#pragma unroll
        for (int nt = 0; nt < NT; ++nt)
            acc[mt][nt] = (floatx4)0.f;

    // ---- per-c2 MFMA phase over the slab.
    auto mfma_c2 = [&](int c2) {
#pragma unroll
        for (int g = 0; g < NG; ++g) {
            short8 bfr[9*GNT];     // batched independent B loads
#pragma unroll
            for (int t = 0; t < 9; ++t)
#pragma unroll
                for (int j = 0; j < GNT; ++j)
                    bfr[t*GNT+j] = *(const short8*)(wt
                        + ((size_t)(c2*9+t)*Co + (g*GNT+j)*16 + col)*32 + quad*8);
#pragma unroll
            for (int t = 0; t < 9; ++t) {
                const int dy = t/3, dx = t - (t/3)*3;
                short8 a[4];
#pragma unroll
                for (int mt = 0; mt < 4; ++mt) {
                    if constexpr (NCHW_IN) {
                        int px = (r+dy)*ROWW + mt*16 + col + dx + 1;
                        int c  = quad ^ (px & 3) ^ ((px >> 2) & 3);
                        a[mt] = *(const short8*)(slab + px*PXB + (c << 4));
                    } else {
                        int px = (r+dy)*ROWW + mt*16 + col + dx;
                        int c  = (c2*4 + quad) ^ (px & (NCB-1));
                        a[mt] = *(const short8*)(slab + px*PXB + (c << 4));
                    }
                }
#pragma unroll
                for (int j = 0; j < GNT; ++j)
#pragma unroll
                    for (int mt = 0; mt < 4; ++mt)
                        acc[mt][g*GNT+j] = __builtin_amdgcn_mfma_f32_16x16x32_bf16(
                            a[mt], bfr[t*GNT+j], acc[mt][g*GNT+j], 0, 0, 0);
            }
        }
    };

    if constexpr (NCHW_IN) {
        // ---- fp32 NCHW feat, CC x {stage 32ch, compute} phases.
        // UNIFORM pair-units: slab row = 68 px covering gw [w0-2, w0+65];
        // pair s covers gw0 = w0-2+2s (EVEN -> aligned float2). 6 rows x 34
        // pairs = 204 units, 4 iters. Loads unconditional (clamped addr),
        // select after -> deep outstanding-load batching (no divergence).
        static_assert(Ci == 64, "NCHW staging is Ci=64 only");
        const float* src = (const float*)(mz ? inB : inA) + (size_t)bz * 64 * H_ * W_;
#pragma unroll
        for (int c2 = 0; c2 < CC; ++c2) {
            if (c2) __syncthreads();             // prior-phase reads done
            const float* chb = src + (size_t)(c2*32 + wid*8) * (H_*W_);
#pragma unroll
            for (int it = 0; it < 4; ++it) {
                int uu   = it*64 + lane;
                bool live = (it < 3) || (lane < 12);     // 204 units
                int row  = uu / 34;
                int s    = uu - row*34;
                int gh   = h0 + row - 1;
                int gw0  = w0 - 2 + 2*s;                 // even
                bool ok  = live && ((unsigned)gh < (unsigned)H_)
                                && ((unsigned)gw0 < (unsigned)(W_-1));
                const float* rp = chb + (size_t)(ok ? gh : 0)*W_ + (ok ? gw0 : 0);
                short8 v0, v1;
#pragma unroll
                for (int j = 0; j < 8; ++j) {
                    float2 f = *(const float2*)(rp + (size_t)j*(H_*W_));
                    v0[j] = __builtin_bit_cast(short,
                                __float2bfloat16(ok ? f.x : 0.f));
                    v1[j] = __builtin_bit_cast(short,
                                __float2bfloat16(ok ? f.y : 0.f));
                }
                if (live) {
                    int pxl = row*ROWW + 2*s;
                    int c0  = wid ^ (pxl & 3) ^ ((pxl >> 2) & 3);
                    *(short8*)(slab + pxl*PXB + (c0 << 4)) = v0;
                    int pxl1 = pxl + 1;
                    int c1  = wid ^ (pxl1 & 3) ^ ((pxl1 >> 2) & 3);
                    *(short8*)(slab + pxl1*PXB + (c1 << 4)) = v1;
                }
            }
            __syncthreads();
            mfma_c2(c2);
        }
    } else {
        // ---- stage slab from padded bf16 NHWC via global_load_lds width=16:
        // linear LDS dest (wave base + lane*16), PRE-SWIZZLED global source
        // (cb = q ^ (pxl & mask)) -> LDS contents identical to old ds_write.
        const __hip_bfloat16* inb = (const __hip_bfloat16*)(mz ? inB : inA)
                                    + (size_t)bz * PH * PW * Ci;
        constexpr int NIT = (SLAB + 4095) / 4096;
#pragma unroll
        for (int it = 0; it < NIT; ++it) {
            int o = it*4096 + tid*16;
            if (o < SLAB) {
                int pxl = o / PXB;
                int row = pxl / ROWW;
                int pxc = pxl - row*ROWW;
                int q   = (o >> 4) & (NCB-1);
                int cb  = q ^ (pxl & (NCB-1));
                gload_lds16(inb + ((size_t)(h0+row)*PW + (w0+pxc))*Ci + cb*8,
                            slab + o);
            }
        }
        __syncthreads();

        if constexpr (Ci >= 32) {
#pragma unroll
            for (int c2 = 0; c2 < CC; ++c2)
                mfma_c2(c2);
        } else {
            // Ci=16: K=32 packs 2 dx taps; half1 upper quads carry zero weights.
            short8 bfr[6*NT];
#pragma unroll
            for (int kc = 0; kc < 6; ++kc)
#pragma unroll
                for (int j = 0; j < NT; ++j)
                    bfr[kc*NT+j] = *(const short8*)(wt
                        + ((size_t)kc*Co + j*16 + col)*32 + quad*8);
#pragma unroll
            for (int kc = 0; kc < 6; ++kc) {
                const int dy = kc >> 1, half = kc & 1;
                const int dxe = half ? 2 : (quad >> 1);
                short8 a[4];
#pragma unroll
                for (int mt = 0; mt < 4; ++mt) {
                    int px = (r+dy)*ROWW + mt*16 + col + dxe;
                    a[mt] = *(const short8*)(slab + px*PXB
                              + (((quad & 1) ^ (px & 1)) << 4));
                }
#pragma unroll
                for (int j = 0; j < NT; ++j)
#pragma unroll
                    for (int mt = 0; mt < 4; ++mt)
                        acc[mt][j] = __builtin_amdgcn_mfma_f32_16x16x32_bf16(
                            a[mt], bfr[kc*NT+j], acc[mt][j], 0, 0, 0);
            }
        }
    }

    if constexpr (!LOSS) {
        __syncthreads();
        char* rt = slab + wid * EPIW;     // per-wave [64 px][Co+8] bf16 tile
#pragma unroll
        for (int nt = 0; nt < NT; ++nt) {
            float bv = bias[nt*16 + col];
#pragma unroll
            for (int mt = 0; mt < 4; ++mt) {
#pragma unroll
                for (int rr = 0; rr < 4; ++rr) {
                    float v = acc[mt][nt][rr] + bv;
                    v = v > 0.f ? v : 0.f;
                    int px = mt*16 + quad*4 + rr;
                    *(__hip_bfloat16*)(rt + (px*(Co+8) + nt*16 + col)*2) =
                        __float2bfloat16(v);
                }
            }
        }
        __hip_bfloat16* ob = outp + (size_t)mz * out_mstride;
        char* grow = (char*)ob
            + (((size_t)bz*PH + (h0 + r + 1))*PW + (w0 + 1))*Co*2;
        constexpr int GB = 64*Co*2;
#pragma unroll
        for (int id = 0; id < GB/1024; ++id) {
            int o  = id*1024 + lane*16;
            int px = o / (Co*2);
            int cb = o - px*(Co*2);
            *(short8*)(grow + o) = *(const short8*)(rt + px*(Co+8)*2 + cb);
        }
    } else {
        // ---- rec -> LDS bf16 [co][row][68] (b64-aligned), barriered
        __syncthreads();                        // all slab reads complete
        __hip_bfloat16* rec = (__hip_bfloat16*)slab;
#pragma unroll
        for (int nt = 0; nt < NT; ++nt) {
            int co = nt*16 + col;
            float bv = bias[co];
#pragma unroll
            for (int mt = 0; mt < 4; ++mt) {
                short4v pk;
#pragma unroll
                for (int rr = 0; rr < 4; ++rr) {
                    float v = acc[mt][nt][rr] + bv;
                    v = v > 0.f ? v : 0.f;
                    pk[rr] = __builtin_bit_cast(short, __float2bfloat16(v));
                }
                *(short4v*)(rec + co*272 + r*68 + mt*16 + quad*4) = pk;
            }
        }
        __syncthreads();

        // ---- coalesced fp32 ref compare: 16 iters, 256B contiguous per co.
        // AVG (mz=1): same tile addresses -> fused = 0.5*(f0+f1).
        float lsum = 0.f;
        const float* refb = (mz ? ref1 : ref0) + (size_t)bz * 64 * H_ * W_;
#pragma unroll
        for (int i = 0; i < 16; ++i) {
            int row = i & 3, cg = i >> 2;
            int co  = cg*16 + wid*4 + quad;
            size_t off = ((size_t)co*H_ + h0 + row)*W_ + w0 + col*4;
            float4 f = *(const float4*)(refb + off);
            short4v pk = *(const short4v*)(rec + co*272 + row*68 + col*4);
            float d0 = f.x - __bfloat162float(__builtin_bit_cast(__hip_bfloat16, pk[0]));
            float d1 = f.y - __bfloat162float(__builtin_bit_cast(__hip_bfloat16, pk[1]));
            float d2 = f.z - __bfloat162float(__builtin_bit_cast(__hip_bfloat16, pk[2]));
            float d3 = f.w - __bfloat162float(__builtin_bit_cast(__hip_bfloat16, pk[3]));
            lsum += d0*d0 + d1*d1 + d2*d2 + d3*d3;
            if constexpr (AVG) {
                if (mz) {
                    const float* othb = other + (size_t)bz * 64 * H_ * W_;
                    float*       avgb = avg_out + (size_t)bz * 64 * H_ * W_;
                    float4 g = *(const float4*)(othb + off);
                    float4 o;
                    o.x = 0.5f*(g.x + f.x);
                    o.y = 0.5f*(g.y + f.y);
                    o.z = 0.5f*(g.z + f.z);
                    o.w = 0.5f*(g.w + f.w);
                    *(float4*)(avgb + off) = o;
                }
            }
        }
#pragma unroll
        for (int off = 32; off > 0; off >>= 1)
            lsum += __shfl_down(lsum, off, 64);
        if (lane == 0) wred[wid] = lsum;
        __syncthreads();
        if (tid == 0)      // 1/NPIX = 2^-24 exact: finalize folded into atomic
            atomicAdd(acc_out, (wred[0] + wred[1] + wred[2] + wred[3])
                               * (1.0f / (float)NPIX));
    }
}

// ---------------------------------------------------------------------------
// XCD-aware tile decode: flat f -> l=(f&7)*256+f/8 (bijective, 2048 blocks).
// Each XCD gets 256 contiguous logical tiles (full x,y planes of 2 z-slices).
// ---------------------------------------------------------------------------
__device__ __forceinline__
void xcd_decode(int& tx, int& ty, int& bz, int& mz)
{
    int f = (blockIdx.z*32 + blockIdx.y)*4 + blockIdx.x;   // grid (4,32,16)
    int l = (f & 7)*256 + (f >> 3);
    tx = l & 3; ty = (l >> 2) & 31;
    int zz = l >> 7;
    bz = zz & 7; mz = zz >> 3;
}

// ---------------------------------------------------------------------------
// Border-zero work item: pad cells of a padded NHWC buffer (772 px / image).
// ---------------------------------------------------------------------------
template<int C>
__device__ __forceinline__ void zb_item(__hip_bfloat16* buf, int idx)
{
    constexpr int CP = C/8;
    int cb   = idx % CP;
    int cell = (idx / CP) % 772;
    int img  = idx / (CP*772);
    int row, colp;
    if (cell < 258)      { row = 0;   colp = cell; }
    else if (cell < 516) { row = 129; colp = cell - 258; }
    else { int r2 = cell - 516; row = 1 + (r2 >> 1); colp = (r2 & 1) ? 257 : 0; }
    short8 z = (short8)0;
    *(short8*)(buf + (((size_t)img*PH + row)*PW + colp)*C + cb*8) = z;
}

// ---------------------------------------------------------------------------
// conv1 kernel: NCHW staging conv + embedded border-zero of BUF1/BUF2.
// ---------------------------------------------------------------------------
__global__ __launch_bounds__(256)
void conv1_kernel(const float* __restrict__ feat0, const float* __restrict__ feat1,
                  const __hip_bfloat16* __restrict__ WT1, const float* __restrict__ b1,
                  __hip_bfloat16* __restrict__ BUF1, __hip_bfloat16* __restrict__ BUF2,
                  size_t b1e)
{
    constexpr int LDSZ = conv_cfg<64,32,false,true>::LDSZ;
    __shared__ alignas(16) char slab[LDSZ + 32];
    __shared__ float wred[4];

    int gtid = ((blockIdx.z*gridDim.y + blockIdx.y)*gridDim.x + blockIdx.x)*256
               + threadIdx.x;
    if      (gtid < 49408) zb_item<32>(BUF1, gtid);
    else if (gtid < 74112) zb_item<16>(BUF2, gtid - 49408);

    int tx, ty, bz, mz;
    xcd_decode(tx, ty, bz, mz);
    conv_tile<64,32,false,true,false>(tx, ty, bz, mz, slab, wred,
        feat0, feat1, WT1, b1, BUF1, b1e,
        nullptr, nullptr, nullptr, nullptr, nullptr);
}

// ---------------------------------------------------------------------------
// conv2/conv3 standalone kernels.
// ---------------------------------------------------------------------------
template<int Ci, int Co>
__global__ __launch_bounds__(256)
void conv_mid(const __hip_bfloat16* __restrict__ inA,
              const __hip_bfloat16* __restrict__ inB,
              const __hip_bfloat16* __restrict__ wt, const float* __restrict__ bias,
              __hip_bfloat16* __restrict__ outp, size_t out_mstride)
{
    constexpr int LDSZ = conv_cfg<Ci,Co,false,false>::LDSZ;
    __shared__ alignas(16) char slab[LDSZ + 32];
    __shared__ float wred[4];
    int tx, ty, bz, mz;
    xcd_decode(tx, ty, bz, mz);
    conv_tile<Ci,Co,false,false,false>(tx, ty, bz, mz, slab, wred,
        inA, inB, wt, bias, outp, out_mstride,
        nullptr, nullptr, nullptr, nullptr, nullptr);
}

// ---------------------------------------------------------------------------
// conv4: LOSS (+AVG) kernel, R2 shape: z=16 grid, runtime mz selects ref and
// (mz==1) the AVG epilogue. Natural regalloc (VGPR ~128, proven).
// ---------------------------------------------------------------------------
template<bool AVG>
__global__ __launch_bounds__(256)
void conv4_kernel(const __hip_bfloat16* __restrict__ BUF1, size_t b1e,
                  const __hip_bfloat16* __restrict__ WT4, const float* __restrict__ b4,
                  const float* __restrict__ feat0, const float* __restrict__ feat1,
                  float* __restrict__ avg_out, float* __restrict__ acc)
{
    constexpr int LDSZ = conv_cfg<32,64,true,false>::LDSZ;   // 34816
    __shared__ alignas(16) char slab[LDSZ + 32];
    __shared__ float wred[4];
    int tx, ty, bz, mz;
    xcd_decode(tx, ty, bz, mz);
    conv_tile<32,64,true,false,AVG>(tx, ty, bz, mz, slab, wred,
        BUF1, BUF1 + b1e, WT4, b4, nullptr, 0,
        feat0, feat1, feat0, avg_out, acc);
}

// ---------------------------------------------------------------------------
// OIHW fp32 -> [KC][Co][32] bf16 B-operand work item.
// ---------------------------------------------------------------------------
template<int Ci, int Co>
__device__ __forceinline__ void wt_item(const float* __restrict__ w,
                                        __hip_bfloat16* __restrict__ wt, int idx)
{
    int kl = idx & 31;
    int co = (idx >> 5) % Co;
    int kc = idx / (32*Co);
    float val = 0.f;
    if constexpr (Ci >= 32) {
        int c2 = kc / 9, t = kc % 9;
        int dy = t/3, dx = t%3;
        int ci = c2*32 + kl;
        val = w[((size_t)(co*Ci + ci)*3 + dy)*3 + dx];
    } else {
        int dy = kc >> 1, half = kc & 1;
        int dx = half*2 + (kl >> 4);
        int ci = kl & 15;
        if (dx < 3) val = w[((size_t)(co*Ci + ci)*3 + dy)*3 + dx];
    }
    wt[idx] = __float2bfloat16(val);
}

// ---------------------------------------------------------------------------
// Setup: weight transforms only (47616 items) + acc=0.
// wt1 18432 | wt2 4608 | wt3 6144 | wt4 18432.
// ---------------------------------------------------------------------------
__global__ __launch_bounds__(256)
void setup_kernel(const float* __restrict__ w1, const float* __restrict__ w2,
                  const float* __restrict__ w3, const float* __restrict__ w4,
                  __hip_bfloat16* WT1, __hip_bfloat16* WT2,
                  __hip_bfloat16* WT3, __hip_bfloat16* WT4,
                  float* acc)
{
    int idx = blockIdx.x*256 + threadIdx.x;
    if (idx == 0) *acc = 0.f;
    if      (idx < 18432) wt_item<64,32>(w1, WT1, idx);
    else if (idx < 23040) wt_item<32,16>(w2, WT2, idx - 18432);
    else if (idx < 29184) wt_item<16,32>(w3, WT3, idx - 23040);
    else if (idx < 47616) wt_item<32,64>(w4, WT4, idx - 29184);
}

// fused_feat = 0.5*(feat0+feat1) exactly. Fallback path only.
__global__ __launch_bounds__(256)
void fused_avg_kernel(const float4* __restrict__ a, const float4* __restrict__ b,
                      float4* __restrict__ o, int n4)
{
    int i = blockIdx.x*256 + threadIdx.x;
    if (i < n4) {
        float4 x = a[i], y = b[i];
        float4 r;
        r.x = 0.5f*(x.x + y.x);
        r.y = 0.5f*(x.y + y.y);
        r.z = 0.5f*(x.z + y.z);
        r.w = 0.5f*(x.w + y.w);
        o[i] = r;
    }
}

extern "C" void kernel_launch(void* const* d_in, const int* in_sizes, int n_in,
                              void* d_out, int out_size, void* d_ws, size_t ws_size,
                              hipStream_t stream)
{
    const float* feat0 = (const float*)d_in[0];
    const float* feat1 = (const float*)d_in[1];
    const float* w1 = (const float*)d_in[2];
    const float* b1 = (const float*)d_in[3];
    const float* w2 = (const float*)d_in[4];
    const float* b2 = (const float*)d_in[5];
    const float* w3 = (const float*)d_in[6];
    const float* b3 = (const float*)d_in[7];
    const float* w4 = (const float*)d_in[8];
    const float* b4 = (const float*)d_in[9];

    float* out = (float*)d_out;
    float* acc = out + NPIX;                 // loss output slot

    // Scratch layout (total 51,612,672 B):
    //   BUF1[2] @ 0 (2 x 17,172,480) | BUF2[2] @ 34344960 (2 x 8,586,240)
    //   WT1 @ 51517440 | WT2 @ 51554304 | WT3 @ 51563520 | WT4 @ 51575808
    constexpr size_t B1B = (size_t)B_*PH*PW*32*2;
    constexpr size_t SCR_SZ = 51612672;
    const bool use_ws = (d_ws != nullptr) && (ws_size >= SCR_SZ);
    char* sb = use_ws ? (char*)d_ws : (char*)d_out;  // fallback: out written last

    __hip_bfloat16* BUF1 = (__hip_bfloat16*)(sb + 0);
    __hip_bfloat16* BUF2 = (__hip_bfloat16*)(sb + 2*B1B);
    __hip_bfloat16* WT1  = (__hip_bfloat16*)(sb + 51517440);
    __hip_bfloat16* WT2  = (__hip_bfloat16*)(sb + 51554304);
    __hip_bfloat16* WT3  = (__hip_bfloat16*)(sb + 51563520);
    __hip_bfloat16* WT4  = (__hip_bfloat16*)(sb + 51575808);

    setup_kernel<<<186, 256, 0, stream>>>(w1, w2, w3, w4,
                                          WT1, WT2, WT3, WT4, acc);

    constexpr size_t B1E = B1B/2;            // bf16-element modality strides
    constexpr size_t B2E = (size_t)B_*PH*PW*16;

    dim3 cgrid(W_/64, H_/4, 2*B_);           // 2048 blocks (both modalities)
    dim3 blk(256);

    conv1_kernel<<<cgrid, blk, 0, stream>>>(feat0, feat1, WT1, b1,
                                            BUF1, BUF2, B1E);
    conv_mid<32,16><<<cgrid, blk, 0, stream>>>(BUF1, BUF1 + B1E, WT2, b2,
                                               BUF2, B2E);
    conv_mid<16,32><<<cgrid, blk, 0, stream>>>(BUF2, BUF2 + B2E, WT3, b3,
                                               BUF1, B1E);
    if (use_ws) {
        conv4_kernel<true><<<cgrid, blk, 0, stream>>>(BUF1, B1E, WT4, b4,
                                                      feat0, feat1, out, acc);
    } else {
        conv4_kernel<false><<<cgrid, blk, 0, stream>>>(BUF1, B1E, WT4, b4,
                                                       feat0, feat1, nullptr, acc);
        int n4 = NPIX/4;
        fused_avg_kernel<<<(n4 + 255)/256, 256, 0, stream>>>(
            (const float4*)feat0, (const float4*)feat1, (float4*)out, n4);
    }
}

// Round 8
// 314.108 us; speedup vs baseline: 1.0134x; 1.0134x over previous
//
#include <hip/hip_runtime.h>
#include <hip/hip_bf16.h>

#define B_ 8
#define H_ 128
#define W_ 256
#define PH 130          // H + 2 zero-pad rows
#define PW 258          // W + 2 zero-pad cols
#define NPIX (B_*64*H_*W_)

typedef short short8  __attribute__((ext_vector_type(8)));  // 8 bf16 (4 VGPRs)
typedef short short4v __attribute__((ext_vector_type(4)));  // 4 bf16 (8 B)
typedef float floatx4 __attribute__((ext_vector_type(4)));  // MFMA C/D

// ---------------------------------------------------------------------------
// Implicit-GEMM 3x3 SAME conv + bias + ReLU, bf16 MFMA 16x16x32, LDS-staged.
// R12: conv1 rebuilt with 8-ROW tiles (grid 1024, wave owns 2 rows).
// Rationale: R7 showed conv1 time is invariant to staging implementation AND
// to HBM traffic (FETCH 171->66MB, dur unchanged) -> per-block convoy cost
// dominates. Halve the block count, double per-block MFMA, better halo
// efficiency (8/10 vs 4/6). Register-managed: GNT=1 (bfr 36), A-frags in
// 4-groups (~150 VGPR -> 3 waves/SIMD = LDS limit 3 blocks/CU @ 43.5KB).
// Per-output accumulation order unchanged -> bit-exact. conv2/3/4 = R7.
// ---------------------------------------------------------------------------
template<int Ci, int Co, bool LOSS, bool NCHW_IN>
struct conv_cfg {
    static constexpr int SCI  = NCHW_IN ? 32 : Ci;     // slab-resident channels
    static constexpr int PXB  = SCI*2;
    static constexpr int ROWW = NCHW_IN ? 68 : 66;     // slab row width (px)
    static constexpr int SLAB = 6*ROWW*PXB;
    static constexpr int EPIW = 64*(Co+8)*2;
    static constexpr int RECB = 64*272*2;
    static constexpr int LDSZ = LOSS ? (RECB > SLAB ? RECB : SLAB)
                                     : (4*EPIW > SLAB ? 4*EPIW : SLAB);
};

// async global->LDS, 16B per lane (literal size arg required).
__device__ __forceinline__
void gload_lds16(const __hip_bfloat16* g, char* l)
{
    __builtin_amdgcn_global_load_lds(
        (const __attribute__((address_space(1))) void*)g,
        (__attribute__((address_space(3))) void*)l, 16, 0, 0);
}

template<int Ci, int Co, bool LOSS, bool NCHW_IN, bool AVG>
__device__ __forceinline__
void conv_tile(int tx, int ty, int bz, int mz,
               char* __restrict__ slab, float* __restrict__ wred,
               const void* __restrict__ inA,    // m0 input (bf16 NHWC)
               const void* __restrict__ inB,    // m1 input
               const __hip_bfloat16* __restrict__ wt,   // [KC][Co][32] bf16
               const float* __restrict__ bias,
               __hip_bfloat16* __restrict__ outp,       // padded NHWC per-m
               size_t out_mstride,
               const float* __restrict__ ref0,          // fp32 NCHW (LOSS)
               const float* __restrict__ ref1,
               const float* __restrict__ other,         // feat0 (AVG, mz=1 only)
               float* __restrict__ avg_out,
               float* __restrict__ acc_out)
{
    constexpr int CC   = (Ci >= 32) ? Ci/32 : 1;
    constexpr int PXB  = conv_cfg<Ci,Co,LOSS,NCHW_IN>::PXB;
    constexpr int NCB  = PXB/16;
    constexpr int ROWW = conv_cfg<Ci,Co,LOSS,NCHW_IN>::ROWW;
    constexpr int SLAB = conv_cfg<Ci,Co,LOSS,NCHW_IN>::SLAB;
    constexpr int NT   = Co/16;
    constexpr int GNT  = (NT >= 2) ? 2 : 1;
    constexpr int NG   = NT / GNT;
    constexpr int EPIW = conv_cfg<Ci,Co,LOSS,NCHW_IN>::EPIW;

    const int tid  = threadIdx.x;
    const int lane = tid & 63;
    const int wid  = tid >> 6;
    const int col  = lane & 15;
    const int quad = lane >> 4;
    const int w0   = tx * 64;
    const int h0   = ty * 4;
    const int r    = wid;

    __syncthreads();        // prior tile's slab reads complete before restage

    floatx4 acc[4][NT];
#pragma unroll
    for (int mt = 0; mt < 4; ++mt)
#pragma unroll
        for (int nt = 0; nt < NT; ++nt)
            acc[mt][nt] = (floatx4)0.f;

    // ---- per-c2 MFMA phase over the slab.
    auto mfma_c2 = [&](int c2) {
#pragma unroll
        for (int g = 0; g < NG; ++g) {
            short8 bfr[9*GNT];     // batched independent B loads
#pragma unroll
            for (int t = 0; t < 9; ++t)
#pragma unroll
                for (int j = 0; j < GNT; ++j)
                    bfr[t*GNT+j] = *(const short8*)(wt
                        + ((size_t)(c2*9+t)*Co + (g*GNT+j)*16 + col)*32 + quad*8);
#pragma unroll
            for (int t = 0; t < 9; ++t) {
                const int dy = t/3, dx = t - (t/3)*3;
                short8 a[4];
#pragma unroll
                for (int mt = 0; mt < 4; ++mt) {
                    int px = (r+dy)*ROWW + mt*16 + col + dx;
                    int c  = (c2*4 + quad) ^ (px & (NCB-1));
                    a[mt] = *(const short8*)(slab + px*PXB + (c << 4));
                }
#pragma unroll
                for (int j = 0; j < GNT; ++j)
#pragma unroll
                    for (int mt = 0; mt < 4; ++mt)
                        acc[mt][g*GNT+j] = __builtin_amdgcn_mfma_f32_16x16x32_bf16(
                            a[mt], bfr[t*GNT+j], acc[mt][g*GNT+j], 0, 0, 0);
            }
        }
    };

    {
        // ---- stage slab from padded bf16 NHWC via global_load_lds width=16:
        // linear LDS dest (wave base + lane*16), PRE-SWIZZLED global source.
        const __hip_bfloat16* inb = (const __hip_bfloat16*)(mz ? inB : inA)
                                    + (size_t)bz * PH * PW * Ci;
        constexpr int NIT = (SLAB + 4095) / 4096;
#pragma unroll
        for (int it = 0; it < NIT; ++it) {
            int o = it*4096 + tid*16;
            if (o < SLAB) {
                int pxl = o / PXB;
                int row = pxl / ROWW;
                int pxc = pxl - row*ROWW;
                int q   = (o >> 4) & (NCB-1);
                int cb  = q ^ (pxl & (NCB-1));
                gload_lds16(inb + ((size_t)(h0+row)*PW + (w0+pxc))*Ci + cb*8,
                            slab + o);
            }
        }
        __syncthreads();

        if constexpr (Ci >= 32) {
#pragma unroll
            for (int c2 = 0; c2 < CC; ++c2)
                mfma_c2(c2);
        } else {
            // Ci=16: K=32 packs 2 dx taps; half1 upper quads carry zero weights.
            short8 bfr[6*NT];
#pragma unroll
            for (int kc = 0; kc < 6; ++kc)
#pragma unroll
                for (int j = 0; j < NT; ++j)
                    bfr[kc*NT+j] = *(const short8*)(wt
                        + ((size_t)kc*Co + j*16 + col)*32 + quad*8);
#pragma unroll
            for (int kc = 0; kc < 6; ++kc) {
                const int dy = kc >> 1, half = kc & 1;
                const int dxe = half ? 2 : (quad >> 1);
                short8 a[4];
#pragma unroll
                for (int mt = 0; mt < 4; ++mt) {
                    int px = (r+dy)*ROWW + mt*16 + col + dxe;
                    a[mt] = *(const short8*)(slab + px*PXB
                              + (((quad & 1) ^ (px & 1)) << 4));
                }
#pragma unroll
                for (int j = 0; j < NT; ++j)
#pragma unroll
                    for (int mt = 0; mt < 4; ++mt)
                        acc[mt][j] = __builtin_amdgcn_mfma_f32_16x16x32_bf16(
                            a[mt], bfr[kc*NT+j], acc[mt][j], 0, 0, 0);
            }
        }
    }

    if constexpr (!LOSS) {
        __syncthreads();
        char* rt = slab + wid * EPIW;     // per-wave [64 px][Co+8] bf16 tile
#pragma unroll
        for (int nt = 0; nt < NT; ++nt) {
            float bv = bias[nt*16 + col];
#pragma unroll
            for (int mt = 0; mt < 4; ++mt) {
#pragma unroll
                for (int rr = 0; rr < 4; ++rr) {
                    float v = acc[mt][nt][rr] + bv;
                    v = v > 0.f ? v : 0.f;
                    int px = mt*16 + quad*4 + rr;
                    *(__hip_bfloat16*)(rt + (px*(Co+8) + nt*16 + col)*2) =
                        __float2bfloat16(v);
                }
            }
        }
        __hip_bfloat16* ob = outp + (size_t)mz * out_mstride;
        char* grow = (char*)ob
            + (((size_t)bz*PH + (h0 + r + 1))*PW + (w0 + 1))*Co*2;
        constexpr int GB = 64*Co*2;
#pragma unroll
        for (int id = 0; id < GB/1024; ++id) {
            int o  = id*1024 + lane*16;
            int px = o / (Co*2);
            int cb = o - px*(Co*2);
            *(short8*)(grow + o) = *(const short8*)(rt + px*(Co+8)*2 + cb);
        }
    } else {
        // ---- rec -> LDS bf16 [co][row][68] (b64-aligned), barriered
        __syncthreads();                        // all slab reads complete
        __hip_bfloat16* rec = (__hip_bfloat16*)slab;
#pragma unroll
        for (int nt = 0; nt < NT; ++nt) {
            int co = nt*16 + col;
            float bv = bias[co];
#pragma unroll
            for (int mt = 0; mt < 4; ++mt) {
                short4v pk;
#pragma unroll
                for (int rr = 0; rr < 4; ++rr) {
                    float v = acc[mt][nt][rr] + bv;
                    v = v > 0.f ? v : 0.f;
                    pk[rr] = __builtin_bit_cast(short, __float2bfloat16(v));
                }
                *(short4v*)(rec + co*272 + r*68 + mt*16 + quad*4) = pk;
            }
        }
        __syncthreads();

        // ---- coalesced fp32 ref compare: 16 iters, 256B contiguous per co.
        // AVG (mz=1): same tile addresses -> fused = 0.5*(f0+f1).
        float lsum = 0.f;
        const float* refb = (mz ? ref1 : ref0) + (size_t)bz * 64 * H_ * W_;
#pragma unroll
        for (int i = 0; i < 16; ++i) {
            int row = i & 3, cg = i >> 2;
            int co  = cg*16 + wid*4 + quad;
            size_t off = ((size_t)co*H_ + h0 + row)*W_ + w0 + col*4;
            float4 f = *(const float4*)(refb + off);
            short4v pk = *(const short4v*)(rec + co*272 + row*68 + col*4);
            float d0 = f.x - __bfloat162float(__builtin_bit_cast(__hip_bfloat16, pk[0]));
            float d1 = f.y - __bfloat162float(__builtin_bit_cast(__hip_bfloat16, pk[1]));
            float d2 = f.z - __bfloat162float(__builtin_bit_cast(__hip_bfloat16, pk[2]));
            float d3 = f.w - __bfloat162float(__builtin_bit_cast(__hip_bfloat16, pk[3]));
            lsum += d0*d0 + d1*d1 + d2*d2 + d3*d3;
            if constexpr (AVG) {
                if (mz) {
                    const float* othb = other + (size_t)bz * 64 * H_ * W_;
                    float*       avgb = avg_out + (size_t)bz * 64 * H_ * W_;
                    float4 g = *(const float4*)(othb + off);
                    float4 o;
                    o.x = 0.5f*(g.x + f.x);
                    o.y = 0.5f*(g.y + f.y);
                    o.z = 0.5f*(g.z + f.z);
                    o.w = 0.5f*(g.w + f.w);
                    *(float4*)(avgb + off) = o;
                }
            }
        }
#pragma unroll
        for (int off = 32; off > 0; off >>= 1)
            lsum += __shfl_down(lsum, off, 64);
        if (lane == 0) wred[wid] = lsum;
        __syncthreads();
        if (tid == 0)      // 1/NPIX = 2^-24 exact: finalize folded into atomic
            atomicAdd(acc_out, (wred[0] + wred[1] + wred[2] + wred[3])
                               * (1.0f / (float)NPIX));
    }
}

// ---------------------------------------------------------------------------
// Border-zero work item: pad cells of a padded NHWC buffer (772 px / image).
// ---------------------------------------------------------------------------
template<int C>
__device__ __forceinline__ void zb_item(__hip_bfloat16* buf, int idx)
{
    constexpr int CP = C/8;
    int cb   = idx % CP;
    int cell = (idx / CP) % 772;
    int img  = idx / (CP*772);
    int row, colp;
    if (cell < 258)      { row = 0;   colp = cell; }
    else if (cell < 516) { row = 129; colp = cell - 258; }
    else { int r2 = cell - 516; row = 1 + (r2 >> 1); colp = (r2 & 1) ? 257 : 0; }
    short8 z = (short8)0;
    *(short8*)(buf + (((size_t)img*PH + row)*PW + colp)*C + cb*8) = z;
}

// ---------------------------------------------------------------------------
// conv1: 8-ROW tiles, fp32 NCHW staging (2 c2 phases), grid (4,16,16)=1024.
// Wave wid owns output rows 2wid, 2wid+1. Slab: 10 rows x 68 px x 32ch
// (43520 B). Staging: uniform float2 pair-units (340), clamped-addr +
// select-after (R6 discipline). Embedded border-zero of BUF1/BUF2.
// ---------------------------------------------------------------------------
__global__ __launch_bounds__(256)
void conv1_kernel(const float* __restrict__ feat0, const float* __restrict__ feat1,
                  const __hip_bfloat16* __restrict__ WT1, const float* __restrict__ b1,
                  __hip_bfloat16* __restrict__ BUF1, __hip_bfloat16* __restrict__ BUF2,
                  size_t b1e)
{
    __shared__ alignas(16) char slab[43520 + 32];

    const int tid  = threadIdx.x;
    const int lane = tid & 63;
    const int wid  = tid >> 6;
    const int col  = lane & 15;
    const int quad = lane >> 4;

    // embedded border-zero (1024 blocks x 256 = 262144 threads >= 74112)
    int gtid = ((blockIdx.z*gridDim.y + blockIdx.y)*gridDim.x + blockIdx.x)*256
               + tid;
    if      (gtid < 49408) zb_item<32>(BUF1, gtid);
    else if (gtid < 74112) zb_item<16>(BUF2, gtid - 49408);

    // XCD-aware decode (1024 % 8 == 0 -> bijective)
    int f = (blockIdx.z*gridDim.y + blockIdx.y)*gridDim.x + blockIdx.x;
    int l = (f & 7)*128 + (f >> 3);
    const int tx = l & 3, ty = (l >> 2) & 15;
    const int zz = l >> 6;
    const int bz = zz & 7, mz = zz >> 3;
    const int w0 = tx*64, h0 = ty*8;

    floatx4 acc[8][2];
#pragma unroll
    for (int mt = 0; mt < 8; ++mt)
#pragma unroll
        for (int nt = 0; nt < 2; ++nt)
            acc[mt][nt] = (floatx4)0.f;

    const float* src = (mz ? feat1 : feat0) + (size_t)bz * 64 * H_ * W_;

#pragma unroll
    for (int c2 = 0; c2 < 2; ++c2) {
        if (c2) __syncthreads();                 // prior-phase reads done
        const float* chb = src + (size_t)(c2*32 + wid*8) * (H_*W_);
        // 10 rows x 34 pairs = 340 uniform units, 6 iters.
#pragma unroll
        for (int it = 0; it < 6; ++it) {
            int uu   = it*64 + lane;
            bool live = (it < 5) || (lane < 20);
            int row  = uu / 34;
            int s    = uu - row*34;
            int gh   = h0 + row - 1;
            int gw0  = w0 - 2 + 2*s;             // even -> aligned float2
            bool ok  = live && ((unsigned)gh < (unsigned)H_)
                            && ((unsigned)gw0 < (unsigned)(W_-1));
            const float* rp = chb + (size_t)(ok ? gh : 0)*W_ + (ok ? gw0 : 0);
            short8 v0, v1;
#pragma unroll
            for (int j = 0; j < 8; ++j) {
                float2 fv = *(const float2*)(rp + (size_t)j*(H_*W_));
                v0[j] = __builtin_bit_cast(short,
                            __float2bfloat16(ok ? fv.x : 0.f));
                v1[j] = __builtin_bit_cast(short,
                            __float2bfloat16(ok ? fv.y : 0.f));
            }
            if (live) {
                int pxl = row*68 + 2*s;
                int c0  = wid ^ (pxl & 3) ^ ((pxl >> 2) & 3);
                *(short8*)(slab + pxl*64 + (c0 << 4)) = v0;
                int p1  = pxl + 1;
                int c1  = wid ^ (p1 & 3) ^ ((p1 >> 2) & 3);
                *(short8*)(slab + p1*64 + (c1 << 4)) = v1;
            }
        }
        __syncthreads();

        // MFMA: NT=2 via GNT=1 g-passes; 8 mt in two 4-groups (reg diet).
#pragma unroll
        for (int g = 0; g < 2; ++g) {
            short8 bfr[9];
#pragma unroll
            for (int t = 0; t < 9; ++t)
                bfr[t] = *(const short8*)(WT1
                    + ((size_t)(c2*9+t)*32 + g*16 + col)*32 + quad*8);
#pragma unroll
            for (int t = 0; t < 9; ++t) {
                const int dy = t/3, dx = t - (t/3)*3;
#pragma unroll
                for (int mh = 0; mh < 2; ++mh) {
                    short8 a[4];
#pragma unroll
                    for (int mq = 0; mq < 4; ++mq) {
                        int mt = mh*4 + mq;
                        int r2 = 2*wid + (mt >> 2);
                        int px = (r2 + dy)*68 + (mt & 3)*16 + col + dx + 1;
                        int c  = quad ^ (px & 3) ^ ((px >> 2) & 3);
                        a[mq] = *(const short8*)(slab + px*64 + (c << 4));
                    }
#pragma unroll
                    for (int mq = 0; mq < 4; ++mq)
                        acc[mh*4+mq][g] = __builtin_amdgcn_mfma_f32_16x16x32_bf16(
                            a[mq], bfr[t], acc[mh*4+mq][g], 0, 0, 0);
                }
            }
        }
    }

    // epilogue: per-wave rt [128 px][40 ch] bf16, then coalesced global copy.
    __syncthreads();                             // all slab MFMA reads done
    char* rt = slab + wid * 10240;
#pragma unroll
    for (int nt = 0; nt < 2; ++nt) {
        float bv = b1[nt*16 + col];
#pragma unroll
        for (int mt = 0; mt < 8; ++mt) {
#pragma unroll
            for (int rr = 0; rr < 4; ++rr) {
                float v = acc[mt][nt][rr] + bv;
                v = v > 0.f ? v : 0.f;
                int px = (mt >> 2)*64 + (mt & 3)*16 + quad*4 + rr;
                *(__hip_bfloat16*)(rt + (px*40 + nt*16 + col)*2) =
                    __float2bfloat16(v);
            }
        }
    }
    __hip_bfloat16* ob = BUF1 + (size_t)mz * b1e;
#pragma unroll
    for (int row2 = 0; row2 < 2; ++row2) {
        char* grow = (char*)(ob
            + (((size_t)bz*PH + (h0 + 2*wid + row2 + 1))*PW + (w0 + 1))*32);
#pragma unroll
        for (int id = 0; id < 4; ++id) {
            int o  = id*1024 + lane*16;
            int px = o >> 6;                     // 64 B per px (32ch bf16)
            int cb = o & 63;
            *(short8*)(grow + o) = *(const short8*)(rt + (row2*64 + px)*80 + cb);
        }
    }
}

// ---------------------------------------------------------------------------
// XCD-aware tile decode for 2048-block grids (4,32,16).
// ---------------------------------------------------------------------------
__device__ __forceinline__
void xcd_decode(int& tx, int& ty, int& bz, int& mz)
{
    int f = (blockIdx.z*32 + blockIdx.y)*4 + blockIdx.x;
    int l = (f & 7)*256 + (f >> 3);
    tx = l & 3; ty = (l >> 2) & 31;
    int zz = l >> 7;
    bz = zz & 7; mz = zz >> 3;
}

// ---------------------------------------------------------------------------
// conv2/conv3 standalone kernels.
// ---------------------------------------------------------------------------
template<int Ci, int Co>
__global__ __launch_bounds__(256)
void conv_mid(const __hip_bfloat16* __restrict__ inA,
              const __hip_bfloat16* __restrict__ inB,
              const __hip_bfloat16* __restrict__ wt, const float* __restrict__ bias,
              __hip_bfloat16* __restrict__ outp, size_t out_mstride)
{
    constexpr int LDSZ = conv_cfg<Ci,Co,false,false>::LDSZ;
    __shared__ alignas(16) char slab[LDSZ + 32];
    __shared__ float wred[4];
    int tx, ty, bz, mz;
    xcd_decode(tx, ty, bz, mz);
    conv_tile<Ci,Co,false,false,false>(tx, ty, bz, mz, slab, wred,
        inA, inB, wt, bias, outp, out_mstride,
        nullptr, nullptr, nullptr, nullptr, nullptr);
}

// ---------------------------------------------------------------------------
// conv4: LOSS (+AVG) kernel, z=16 grid, runtime mz selects ref and (mz==1)
// the AVG epilogue. Natural regalloc (VGPR ~128, proven).
// ---------------------------------------------------------------------------
template<bool AVG>
__global__ __launch_bounds__(256)
void conv4_kernel(const __hip_bfloat16* __restrict__ BUF1, size_t b1e,
                  const __hip_bfloat16* __restrict__ WT4, const float* __restrict__ b4,
                  const float* __restrict__ feat0, const float* __restrict__ feat1,
                  float* __restrict__ avg_out, float* __restrict__ acc)
{
    constexpr int LDSZ = conv_cfg<32,64,true,false>::LDSZ;   // 34816
    __shared__ alignas(16) char slab[LDSZ + 32];
    __shared__ float wred[4];
    int tx, ty, bz, mz;
    xcd_decode(tx, ty, bz, mz);
    conv_tile<32,64,true,false,AVG>(tx, ty, bz, mz, slab, wred,
        BUF1, BUF1 + b1e, WT4, b4, nullptr, 0,
        feat0, feat1, feat0, avg_out, acc);
}

// ---------------------------------------------------------------------------
// OIHW fp32 -> [KC][Co][32] bf16 B-operand work item.
// ---------------------------------------------------------------------------
template<int Ci, int Co>
__device__ __forceinline__ void wt_item(const float* __restrict__ w,
                                        __hip_bfloat16* __restrict__ wt, int idx)
{
    int kl = idx & 31;
    int co = (idx >> 5) % Co;
    int kc = idx / (32*Co);
    float val = 0.f;
    if constexpr (Ci >= 32) {
        int c2 = kc / 9, t = kc % 9;
        int dy = t/3, dx = t%3;
        int ci = c2*32 + kl;
        val = w[((size_t)(co*Ci + ci)*3 + dy)*3 + dx];
    } else {
        int dy = kc >> 1, half = kc & 1;
        int dx = half*2 + (kl >> 4);
        int ci = kl & 15;
        if (dx < 3) val = w[((size_t)(co*Ci + ci)*3 + dy)*3 + dx];
    }
    wt[idx] = __float2bfloat16(val);
}

// ---------------------------------------------------------------------------
// Setup: weight transforms only (47616 items) + acc=0.
// ---------------------------------------------------------------------------
__global__ __launch_bounds__(256)
void setup_kernel(const float* __restrict__ w1, const float* __restrict__ w2,
                  const float* __restrict__ w3, const float* __restrict__ w4,
                  __hip_bfloat16* WT1, __hip_bfloat16* WT2,
                  __hip_bfloat16* WT3, __hip_bfloat16* WT4,
                  float* acc)
{
    int idx = blockIdx.x*256 + threadIdx.x;
    if (idx == 0) *acc = 0.f;
    if      (idx < 18432) wt_item<64,32>(w1, WT1, idx);
    else if (idx < 23040) wt_item<32,16>(w2, WT2, idx - 18432);
    else if (idx < 29184) wt_item<16,32>(w3, WT3, idx - 23040);
    else if (idx < 47616) wt_item<32,64>(w4, WT4, idx - 29184);
}

// fused_feat = 0.5*(feat0+feat1) exactly. Fallback path only.
__global__ __launch_bounds__(256)
void fused_avg_kernel(const float4* __restrict__ a, const float4* __restrict__ b,
                      float4* __restrict__ o, int n4)
{
    int i = blockIdx.x*256 + threadIdx.x;
    if (i < n4) {
        float4 x = a[i], y = b[i];
        float4 r;
        r.x = 0.5f*(x.x + y.x);
        r.y = 0.5f*(x.y + y.y);
        r.z = 0.5f*(x.z + y.z);
        r.w = 0.5f*(x.w + y.w);
        o[i] = r;
    }
}

extern "C" void kernel_launch(void* const* d_in, const int* in_sizes, int n_in,
                              void* d_out, int out_size, void* d_ws, size_t ws_size,
                              hipStream_t stream)
{
    const float* feat0 = (const float*)d_in[0];
    const float* feat1 = (const float*)d_in[1];
    const float* w1 = (const float*)d_in[2];
    const float* b1 = (const float*)d_in[3];
    const float* w2 = (const float*)d_in[4];
    const float* b2 = (const float*)d_in[5];
    const float* w3 = (const float*)d_in[6];
    const float* b3 = (const float*)d_in[7];
    const float* w4 = (const float*)d_in[8];
    const float* b4 = (const float*)d_in[9];

    float* out = (float*)d_out;
    float* acc = out + NPIX;                 // loss output slot

    // Scratch layout (total 51,612,672 B):
    //   BUF1[2] @ 0 (2 x 17,172,480) | BUF2[2] @ 34344960 (2 x 8,586,240)
    //   WT1 @ 51517440 | WT2 @ 51554304 | WT3 @ 51563520 | WT4 @ 51575808
    constexpr size_t B1B = (size_t)B_*PH*PW*32*2;
    constexpr size_t SCR_SZ = 51612672;
    const bool use_ws = (d_ws != nullptr) && (ws_size >= SCR_SZ);
    char* sb = use_ws ? (char*)d_ws : (char*)d_out;  // fallback: out written last

    __hip_bfloat16* BUF1 = (__hip_bfloat16*)(sb + 0);
    __hip_bfloat16* BUF2 = (__hip_bfloat16*)(sb + 2*B1B);
    __hip_bfloat16* WT1  = (__hip_bfloat16*)(sb + 51517440);
    __hip_bfloat16* WT2  = (__hip_bfloat16*)(sb + 51554304);
    __hip_bfloat16* WT3  = (__hip_bfloat16*)(sb + 51563520);
    __hip_bfloat16* WT4  = (__hip_bfloat16*)(sb + 51575808);

    setup_kernel<<<186, 256, 0, stream>>>(w1, w2, w3, w4,
                                          WT1, WT2, WT3, WT4, acc);

    constexpr size_t B1E = B1B/2;            // bf16-element modality strides
    constexpr size_t B2E = (size_t)B_*PH*PW*16;

    dim3 cgrid1(W_/64, H_/8, 2*B_);          // 1024 blocks (8-row conv1)
    dim3 cgrid(W_/64, H_/4, 2*B_);           // 2048 blocks
    dim3 blk(256);

    conv1_kernel<<<cgrid1, blk, 0, stream>>>(feat0, feat1, WT1, b1,
                                             BUF1, BUF2, B1E);
    conv_mid<32,16><<<cgrid, blk, 0, stream>>>(BUF1, BUF1 + B1E, WT2, b2,
                                               BUF2, B2E);
    conv_mid<16,32><<<cgrid, blk, 0, stream>>>(BUF2, BUF2 + B2E, WT3, b3,
                                               BUF1, B1E);
    if (use_ws) {
        conv4_kernel<true><<<cgrid, blk, 0, stream>>>(BUF1, B1E, WT4, b4,
                                                      feat0, feat1, out, acc);
    } else {
        conv4_kernel<false><<<cgrid, blk, 0, stream>>>(BUF1, B1E, WT4, b4,
                                                       feat0, feat1, nullptr, acc);
        int n4 = NPIX/4;
        fused_avg_kernel<<<(n4 + 255)/256, 256, 0, stream>>>(
            (const float4*)feat0, (const float4*)feat1, (float4*)out, n4);
    }
}